// Round 8
// baseline (511.914 us; speedup 1.0000x reference)
//
#include <hip/hip_runtime.h>
#include <hip/hip_bf16.h>

#define NTOT 8192
#define DDIM 256
#define RT 32                    // rows per wave (one 32x32 MFMA M)
#define JSPLIT 8
#define JCHUNK (NTOT / JSPLIT)   // 1024 j per wave
#define NBODY (JCHUNK / 16)      // 64 bodies (K=16 each)
#define JBSTR 520                // hTf2 nb-stride in frags (512 + pad, breaks 512KB alias)

typedef __attribute__((ext_vector_type(8)))  short short8;
typedef __attribute__((ext_vector_type(16))) float floatx16;

// ------- per-row scores + exp tables: rc=(e^s1, e^.01s1, e^-s1), etab=(e^s2, e^.01s2)
__global__ __launch_bounds__(256) void gat_scores(const float* __restrict__ h,
                                                  const float* __restrict__ a,
                                                  float4* __restrict__ rc,
                                                  float2* __restrict__ etab) {
  int row  = blockIdx.x * 4 + (threadIdx.x >> 6);
  int lane = threadIdx.x & 63;
  const float* hr = h + (size_t)row * DDIM;
  float p1 = 0.f, p2 = 0.f;
#pragma unroll
  for (int k = 0; k < DDIM / 64; ++k) {
    int idx  = lane + 64 * k;
    float hv = hr[idx];
    p1 += hv * a[idx];
    p2 += hv * a[DDIM + idx];
  }
#pragma unroll
  for (int off = 32; off > 0; off >>= 1) {
    p1 += __shfl_down(p1, off, 64);
    p2 += __shfl_down(p2, off, 64);
  }
  if (lane == 0) {
    rc[row]   = make_float4(__expf(p1), __expf(0.01f * p1), __expf(-p1), 0.f);
    etab[row] = make_float2(__expf(p2), __expf(0.01f * p2));
  }
}

// ---------------- pack h -> 32x32x16 B-fragment-major bf16 ------------------
// frag (nb, jb): elem(lane, i) = H[jb*16 + (lane>>5)*8 + i][nb*32 + (lane&31)]
// stored at hTf2[((size_t)nb*JBSTR + jb)*512 + lane*8 + i]
__global__ __launch_bounds__(256) void gat_hpack(const float* __restrict__ h,
                                                 ushort* __restrict__ hTf2) {
  __shared__ float tile[64][257];
  const int t    = threadIdx.x;
  const int lane = t & 63;
  const int w    = t >> 6;
  const int half = lane >> 5;
  const int l31  = lane & 31;
  const int j0   = blockIdx.x * 64;

#pragma unroll
  for (int it = 0; it < 16; ++it) {
    int r = it * 4 + w;
    float4 v = *(const float4*)(h + (size_t)(j0 + r) * DDIM + lane * 4);
    tile[r][lane * 4 + 0] = v.x; tile[r][lane * 4 + 1] = v.y;
    tile[r][lane * 4 + 2] = v.z; tile[r][lane * 4 + 3] = v.w;
  }
  __syncthreads();

  const int jb = blockIdx.x * 4 + w;   // this wave's frag j-index
#pragma unroll
  for (int nb = 0; nb < 8; ++nb) {
    short8 vv;
#pragma unroll
    for (int i = 0; i < 8; ++i) {
      float f = tile[w * 16 + half * 8 + i][nb * 32 + l31];
      __hip_bfloat16 b = __float2bfloat16(f);
      vv[i] = *(short*)&b;
    }
    *(short8*)(hTf2 + ((size_t)nb * JBSTR + jb) * 512 + lane * 8) = vv;
  }
}

// ---------------- fused mask+softmax+P@h, 32x32x16 MFMA, no LDS/barriers ----
// 512 blocks x 256 thr; wave wg = bx*4+w: rows [rt*32,+32), j in [js*1024,+1024).
// Each lane owns ONE row. adj read directly (fused pack). Partials to ws.
__global__ __launch_bounds__(256, 2) void gat_attn(const ushort* __restrict__ hTf2,
                                                   const int*   __restrict__ adj,
                                                   const float4* __restrict__ rc,
                                                   const float* __restrict__ etabf,
                                                   float* __restrict__ part,
                                                   float* __restrict__ lpart) {
  const int t    = threadIdx.x;
  const int lane = t & 63;
  const int w    = t >> 6;
  const int half = lane >> 5;
  const int l31  = lane & 31;
  const int wg   = blockIdx.x * 4 + w;
  const int rtile = wg & 255;
  const int js    = wg >> 8;
  const int rbase = rtile * RT;
  const int jbase = js * JCHUNK;
  const int row   = rbase + l31;

  const float4 rcv = rc[row];
  const float E1 = rcv.x, E2 = rcv.y, T = rcv.z;

  const int*    adjp = adj + (size_t)row * NTOT + jbase + half * 8;
  const float*  etp  = etabf + 2 * (jbase + half * 8);
  const ushort* bfp  = hTf2 + (size_t)(js * 64) * 512 + lane * 8;

  floatx16 acc[8];
#pragma unroll
  for (int nb = 0; nb < 8; ++nb)
#pragma unroll
    for (int r = 0; r < 16; ++r) acc[nb][r] = 0.f;
  float lp = 0.f;

  // depth-2 prefetch rings (parity-indexed, statically unrolled)
  int4   aR[2][2];
  float4 eR[2][4];
#pragma unroll
  for (int p = 0; p < 2; ++p) {
    aR[p][0] = ((const int4*)(adjp + p * 16))[0];
    aR[p][1] = ((const int4*)(adjp + p * 16 + 4))[0];
    eR[p][0] = ((const float4*)(etp + p * 32))[0];
    eR[p][1] = ((const float4*)(etp + p * 32 + 4))[0];
    eR[p][2] = ((const float4*)(etp + p * 32 + 8))[0];
    eR[p][3] = ((const float4*)(etp + p * 32 + 12))[0];
  }

#define BODY(jt, P)                                                            \
  {                                                                            \
    /* B-frag loads for this body (16B/lane, 1KB/frag, L2-resident) */         \
    short8 bfr[8];                                                             \
    const ushort* bp = bfp + (size_t)(jt) * 512;                               \
    _Pragma("unroll")                                                          \
    for (int nb = 0; nb < 8; ++nb)                                             \
      bfr[nb] = *(const short8*)(bp + (size_t)nb * (JBSTR * 512));             \
    /* P-build: one row per lane */                                            \
    const int* am = (const int*)aR[P];                                         \
    short8 pa;                                                                 \
    _Pragma("unroll")                                                          \
    for (int i = 0; i < 8; ++i) {                                              \
      const float t1 = eR[P][i >> 1][(i & 1) ? 2 : 0];                         \
      const float t2 = eR[P][i >> 1][(i & 1) ? 3 : 1];                         \
      float v = (t1 > T) ? E1 * t1 : E2 * t2;                                  \
      v = (am[i] > 0) ? v : 0.f;                                               \
      lp += v;                                                                 \
      __hip_bfloat16 b = __float2bfloat16(v);                                  \
      pa[i] = *(short*)&b;                                                     \
    }                                                                          \
    /* depth-2 prefetch into same parity slot */                               \
    if ((jt) + 2 < NBODY) {                                                    \
      aR[P][0] = ((const int4*)(adjp + ((jt) + 2) * 16))[0];                   \
      aR[P][1] = ((const int4*)(adjp + ((jt) + 2) * 16 + 4))[0];               \
      const float* en = etp + ((jt) + 2) * 32;                                 \
      eR[P][0] = ((const float4*)(en))[0];                                     \
      eR[P][1] = ((const float4*)(en + 4))[0];                                 \
      eR[P][2] = ((const float4*)(en + 8))[0];                                 \
      eR[P][3] = ((const float4*)(en + 12))[0];                                \
    }                                                                          \
    _Pragma("unroll")                                                          \
    for (int nb = 0; nb < 8; ++nb)                                             \
      acc[nb] = __builtin_amdgcn_mfma_f32_32x32x16_bf16(pa, bfr[nb],           \
                                                        acc[nb], 0, 0, 0);     \
  }

  for (int jt = 0; jt < NBODY; jt += 2) {
    BODY(jt, 0)
    BODY(jt + 1, 1)
  }
#undef BODY

  // ---- row sums: lane l and l^32 share a row ----
  lp += __shfl_xor(lp, 32, 64);
  if (lane < 32) lpart[(size_t)js * NTOT + rbase + lane] = lp;

  // ---- partial store: C/D layout col=lane&31, row=(reg&3)+8*(reg>>2)+4*half
  float* pp = part + ((size_t)js * NTOT + rbase) * DDIM;
#pragma unroll
  for (int nb = 0; nb < 8; ++nb)
#pragma unroll
    for (int reg = 0; reg < 16; ++reg) {
      int rloc = (reg & 3) + 8 * (reg >> 2) + 4 * half;
      pp[(size_t)rloc * DDIM + nb * 32 + l31] = acc[nb][reg];
    }
}

// ---------------- reduce j-split partials + softmax divide ------------------
__global__ __launch_bounds__(256) void gat_reduce(const float* __restrict__ part,
                                                  const float* __restrict__ lpart,
                                                  float* __restrict__ out) {
  const int row = blockIdx.x;
  const int t   = threadIdx.x;
  float l = 0.f;
#pragma unroll
  for (int js = 0; js < JSPLIT; ++js) l += lpart[(size_t)js * NTOT + row];
  float s = 0.f;
#pragma unroll
  for (int js = 0; js < JSPLIT; ++js)
    s += part[((size_t)js * NTOT + row) * DDIM + t];
  out[(size_t)row * DDIM + t] = s / l;
}

extern "C" void kernel_launch(void* const* d_in, const int* in_sizes, int n_in,
                              void* d_out, int out_size, void* d_ws, size_t ws_size,
                              hipStream_t stream) {
  const float* h   = (const float*)d_in[0];
  const int*   adj = (const int*)d_in[1];
  const float* a   = (const float*)d_in[2];
  float* out = (float*)d_out;
  char* ws = (char*)d_ws;

  float4* rc    = (float4*)(ws);               // 128 KB @ 0
  float2* etab  = (float2*)(ws + (256 << 10)); // 64 KB  @ 256K
  ushort* hTf2  = (ushort*)(ws + (1 << 20));   // 8*520 KB ≈ 4.2 MB @ 1M
  float*  part  = (float*)(ws + (8 << 20));    // 64 MB  @ 8M
  float*  lpart = (float*)(ws + (80 << 20));   // 256 KB @ 80M

  gat_scores<<<NTOT / 4, 256, 0, stream>>>(h, a, rc, etab);
  gat_hpack<<<NTOT / 64, 256, 0, stream>>>(h, hTf2);
  gat_attn<<<512, 256, 0, stream>>>(hTf2, adj, rc, (const float*)etab, part, lpart);
  gat_reduce<<<NTOT, 256, 0, stream>>>(part, lpart, out);
}